// Round 14
// baseline (122.722 us; speedup 1.0000x reference)
//
#include <hip/hip_runtime.h>
#include <hip/hip_cooperative_groups.h>
#include <math.h>
#include <stdint.h>

namespace cg = cooperative_groups;

#define NANCH 49104
#define NCLS 80
#define KSEL 100
#define NFLAT (NCLS * KSEL)
#define PREDC 84
#define NB 8
#define ECAP 128
#define BATF4 (NANCH * (PREDC / 4))        // 1,031,184 float4s per batch
#define BPB 128                             // parts per batch (NB*BPB = 1024 blocks)
#define PCAP 24                             // per-(class,part) slice cap (lambda=2.38)
#define FASTN 512                           // fast-select list cap (n mean ~305)
#define RMAX 8                              // FASTN/64 register candidates per lane
#define CGRP 5
#define NCHUNK (NCLS / CGRP)                // 16
#define GRID_TOTAL (NB * BPB)               // 1024
// z-threshold: score > sigmoid(2.5)=0.924; per-class 100th score at z=2.873±0.032
#define THRL 2.5f

struct DimsTable { float d[5][9][2]; };
struct KT { uint32_t key; int tie; };
typedef unsigned long long u64;

__device__ __forceinline__ uint32_t f2key(float f) {
    uint32_t u = __float_as_uint(f);
    return u ^ (uint32_t((int32_t)u >> 31) | 0x80000000u);
}
__device__ __forceinline__ float key2f(uint32_t k) {
    uint32_t u = (k & 0x80000000u) ? (k ^ 0x80000000u) : ~k;
    return __uint_as_float(u);
}
__device__ __forceinline__ float sigm(float x) { return 1.0f / (1.0f + expf(-x)); }

__device__ __forceinline__ void decode_box(const float4 pv, int n,
                                           const DimsTable& dt, float box[4]) {
    int lev, base, fw, stride;
    if (n < 36864)      { lev = 0; base = 0;     fw = 64; stride = 8;   }
    else if (n < 46080) { lev = 1; base = 36864; fw = 32; stride = 16;  }
    else if (n < 48384) { lev = 2; base = 46080; fw = 16; stride = 32;  }
    else if (n < 48960) { lev = 3; base = 48384; fw = 8;  stride = 64;  }
    else                { lev = 4; base = 48960; fw = 4;  stride = 128; }
    int i = n - base;
    int k = i % 9;
    int cell = i / 9;
    int xq = cell % fw, yq = cell / fw;
    float cx = ((float)xq + 0.5f) * (float)stride;
    float cy = ((float)yq + 0.5f) * (float)stride;
    float aw = dt.d[lev][k][0];
    float ah = dt.d[lev][k][1];
    float tx = __fmul_rn(pv.x, 0.1f);
    float ty = __fmul_rn(pv.y, 0.1f);
    float tw = __fmul_rn(pv.z, 0.2f);
    float th = __fmul_rn(pv.w, 0.2f);
    float px = __fadd_rn(__fmul_rn(tx, aw), cx);
    float py = __fadd_rn(__fmul_rn(ty, ah), cy);
    float pw = __fmul_rn(expf(tw), aw);
    float ph = __fmul_rn(expf(th), ah);
    float hw = __fmul_rn(pw, 0.5f);
    float hh = __fmul_rn(ph, 0.5f);
    box[0] = __fsub_rn(px, hw);
    box[1] = __fsub_rn(py, hh);
    box[2] = __fadd_rn(px, hw);
    box[3] = __fadd_rn(py, hh);
}

// ------------------------- shared-memory phase structs -----------------------
struct alignas(16) SelSh {
    int hist[2048];           // overlaid as u64 list64[FASTN] in fast path
    int suffix[256];
    uint32_t candKey[KSEL];
    int candIdx[KSEL];
    uint32_t eIdx[ECAP];
    uint32_t sKey[KSEL];
    int sIdx[KSEL];
    int cntG, cntE, krem, newkrem, digit, flast, rmin;
    uint32_t prefix, thrKey;
};
struct alignas(16) ScanSh {
    uint2 buck[NCLS][PCAP];   // 15360 B
    int lcnt[NCLS];
};
struct alignas(16) NmsSh {
    SelSh sel;
    uint16_t prank[4][FASTN];
    int wtot[4];
    int oflAny;
    float sbox[KSEL][4];
    float sarea[KSEL];
    int sconf[KSEL];
    alignas(16) uint32_t sup[KSEL][4];
    uint32_t keepm[4];
};
struct alignas(16) ChunkSh {
    u64 list64[FASTN];
    uint16_t prank[4][FASTN];
    int csh[CGRP + 1];
    u64 osel[KSEL];
};
struct alignas(16) MergeSh {
    u64 lst[NCHUNK][KSEL];
    int ln[NCHUNK];
    u64 osel[KSEL];
    int okcnt;
};
union AllSh { ScanSh scan; NmsSh nms; ChunkSh chunk; MergeSh merge; };

// ---------- exact top-K fallback (full rescan; never taken on this data) -----
template <typename G>
__device__ int block_select(G get, int N, int K, SelSh& sh) {
    const int tid = threadIdx.x;
    int Ksel = (N < K) ? N : K;
    if (Ksel <= 0) return 0;

    if (N <= K) {
        if (tid < N) { KT e = get(tid); sh.candKey[tid] = e.key; sh.candIdx[tid] = e.tie; }
        __syncthreads();
        if (tid < N) {
            uint32_t mk = sh.candKey[tid]; int mi = sh.candIdx[tid];
            int rank = 0;
            for (int j = 0; j < N; ++j) {
                uint32_t kj = sh.candKey[j]; int ij = sh.candIdx[j];
                rank += (kj > mk) || (kj == mk && ij < mi);
            }
            sh.sKey[rank] = mk; sh.sIdx[rank] = mi;
        }
        __syncthreads();
        return Ksel;
    }

    if (tid == 0) { sh.krem = K; sh.prefix = 0; }
    for (int pass = 0; pass < 3; ++pass) {
        const int bins   = (pass == 2) ? 1024 : 2048;
        const int dshift = (pass == 0) ? 21 : (pass == 1 ? 10 : 0);
        const int fshift = (pass == 1) ? 21 : 10;
        const int dmask  = bins - 1;
        for (int j = tid; j < bins; j += 256) sh.hist[j] = 0;
        __syncthreads();
        const uint32_t pref = sh.prefix;
        for (int i = tid; i < N; i += 256) {
            uint32_t key = get(i).key;
            if (pass == 0) atomicAdd(&sh.hist[(key >> dshift) & dmask], 1);
            else if ((key >> fshift) == pref) atomicAdd(&sh.hist[(key >> dshift) & dmask], 1);
        }
        __syncthreads();
        const int cpb = bins / 256;
        const int base = tid * cpb;
        int lsum = 0;
        for (int j = 0; j < cpb; ++j) lsum += sh.hist[base + j];
        sh.suffix[tid] = lsum;
        __syncthreads();
        for (int off = 1; off < 256; off <<= 1) {
            int v = (tid + off < 256) ? sh.suffix[tid + off] : 0;
            __syncthreads();
            sh.suffix[tid] += v;
            __syncthreads();
        }
        {
            int cum = sh.suffix[tid] - lsum;
            const int krem = sh.krem;
            for (int j = cpb - 1; j >= 0; --j) {
                int cnt = sh.hist[base + j];
                if (cnt > 0 && cum < krem && cum + cnt >= krem) {
                    sh.digit = base + j;
                    sh.newkrem = krem - cum;
                }
                cum += cnt;
            }
        }
        __syncthreads();
        if (tid == 0) {
            sh.krem = sh.newkrem;
            if (pass == 0)      sh.prefix = (uint32_t)sh.digit;
            else if (pass == 1) sh.prefix = (sh.prefix << 11) | (uint32_t)sh.digit;
            else                sh.thrKey = (sh.prefix << 10) | (uint32_t)sh.digit;
        }
        __syncthreads();
    }

    if (tid == 0) { sh.cntG = 0; sh.cntE = 0; }
    __syncthreads();
    const uint32_t thr = sh.thrKey;
    for (int i = tid; i < N; i += 256) {
        KT e = get(i);
        if (e.key > thr) {
            int g = atomicAdd(&sh.cntG, 1);
            sh.candKey[g] = e.key; sh.candIdx[g] = e.tie;
        } else if (e.key == thr) {
            int idx = atomicAdd(&sh.cntE, 1);
            if (idx < ECAP) sh.eIdx[idx] = (uint32_t)e.tie;
        }
    }
    __syncthreads();
    const int need = sh.krem;
    const int nG = K - need;
    if (sh.cntE <= ECAP) {
        const int ce = sh.cntE;
        if (tid < ce) {
            uint32_t my = sh.eIdx[tid];
            int rank = 0;
            for (int j = 0; j < ce; ++j) rank += (sh.eIdx[j] < my);
            if (rank < need) { sh.candKey[nG + rank] = thr; sh.candIdx[nG + rank] = (int)my; }
        }
    } else {
        if (tid == 0) sh.flast = -1;
        __syncthreads();
        for (int t = 0; t < need; ++t) {
            if (tid == 0) sh.rmin = 0x7FFFFFFF;
            __syncthreads();
            const int fl = sh.flast;
            int lmin = 0x7FFFFFFF;
            for (int i = tid; i < N; i += 256) {
                KT e = get(i);
                if (e.key == thr && e.tie > fl) lmin = min(lmin, e.tie);
            }
            atomicMin(&sh.rmin, lmin);
            __syncthreads();
            if (tid == 0) { sh.candKey[nG + t] = thr; sh.candIdx[nG + t] = sh.rmin; sh.flast = sh.rmin; }
            __syncthreads();
        }
    }
    __syncthreads();
    if (tid < K) {
        uint32_t mk = sh.candKey[tid]; int mi = sh.candIdx[tid];
        int rank = 0;
        for (int j = 0; j < K; ++j) {
            uint32_t kj = sh.candKey[j]; int ij = sh.candIdx[j];
            rank += (kj > mk) || (kj == mk && ij < mi);
        }
        sh.sKey[rank] = mk; sh.sIdx[rank] = mi;
    }
    __syncthreads();
    return Ksel;
}

// ---------------- phase 1: coalesced scan -> static slices -------------------
__device__ __forceinline__ void procf4(float4 p, int v, int b,
                                       int* lcnt, uint2 (*buck)[PCAP]) {
    uint32_t q = (uint32_t)v / 21u;
    uint32_t j = (uint32_t)v - q * 21u;
    if (j == 0u) return;
    bool c0 = p.x > THRL, c1 = p.y > THRL, c2 = p.z > THRL, c3 = p.w > THRL;
    if (!(c0 | c1 | c2 | c3)) return;
    uint32_t row = q - (uint32_t)b * (uint32_t)NANCH;
    int cbase = ((int)j - 1) * 4;
    float vv[4] = {p.x, p.y, p.z, p.w};
    bool pp[4] = {c0, c1, c2, c3};
#pragma unroll
    for (int k = 0; k < 4; ++k) {
        if (pp[k]) {
            int c = cbase + k;
            uint32_t key = f2key(sigm(vv[k]));
            int slot = atomicAdd(&lcnt[c], 1);
            if (slot < PCAP) buck[c][slot] = make_uint2(key, row);
            // overflow: count kept in lcnt; flagged at flush -> exact fallback
        }
    }
}

__device__ void phase_scan(const float4* __restrict__ predv,
                           uint2* __restrict__ cand2, int* __restrict__ cnt2,
                           int blk, char* smemc) {
    ScanSh& sh = *reinterpret_cast<ScanSh*>(smemc);
    const int tid = threadIdx.x;
    const int b = blk / BPB;
    const int part = blk - b * BPB;
    const int CH = (BATF4 + BPB - 1) / BPB;

    for (int j = tid; j < NCLS; j += 256) sh.lcnt[j] = 0;
    __syncthreads();

    int s = b * BATF4 + part * CH;
    int e = b * BATF4 + BATF4;
    if (s + CH < e) e = s + CH;

    int v = s + tid;
    for (; v + 7 * 256 < e; v += 8 * 256) {
        float4 a0 = predv[v];
        float4 a1 = predv[v + 1 * 256];
        float4 a2 = predv[v + 2 * 256];
        float4 a3 = predv[v + 3 * 256];
        float4 a4 = predv[v + 4 * 256];
        float4 a5 = predv[v + 5 * 256];
        float4 a6 = predv[v + 6 * 256];
        float4 a7 = predv[v + 7 * 256];
        procf4(a0, v,           b, sh.lcnt, sh.buck);
        procf4(a1, v + 1 * 256, b, sh.lcnt, sh.buck);
        procf4(a2, v + 2 * 256, b, sh.lcnt, sh.buck);
        procf4(a3, v + 3 * 256, b, sh.lcnt, sh.buck);
        procf4(a4, v + 4 * 256, b, sh.lcnt, sh.buck);
        procf4(a5, v + 5 * 256, b, sh.lcnt, sh.buck);
        procf4(a6, v + 6 * 256, b, sh.lcnt, sh.buck);
        procf4(a7, v + 7 * 256, b, sh.lcnt, sh.buck);
    }
    for (; v < e; v += 256)
        procf4(predv[v], v, b, sh.lcnt, sh.buck);
    __syncthreads();

    if (tid < NCLS) {
        int lc = sh.lcnt[tid];
        int val = (lc > PCAP) ? (PCAP | 0x10000) : lc;   // overflow flag bit 16
        cnt2[((size_t)b * NCLS + tid) * BPB + part] = val;
    }
    for (int x = tid; x < NCLS * PCAP; x += 256) {
        int c = x / PCAP;
        int k = x - c * PCAP;
        int lc = sh.lcnt[c];
        if (lc > PCAP) lc = PCAP;
        if (k < lc)
            cand2[((size_t)(b * NCLS + c) * PCAP + k) * BPB + part] = sh.buck[c][k];
    }
}

// ---------------- phase 2: gather + rank-select + NMS ------------------------
__device__ void phase_nms(const float* __restrict__ pred,
                          const uint2* __restrict__ cand2,
                          const int* __restrict__ cnt2,
                          float* __restrict__ cls_boxes,
                          uint32_t* __restrict__ posKeyC,
                          uint32_t* __restrict__ posFlatC,
                          int* __restrict__ posCntC,
                          const DimsTable& dt, int blk, char* smemc) {
    NmsSh& sh = *reinterpret_cast<NmsSh*>(smemc);
    const int b = blk / NCLS;
    const int c = blk - b * NCLS;
    const int tid = threadIdx.x;
    const int bc = b * NCLS + c;
    const int lane = tid & 63;
    const int wid = tid >> 6;

    if (tid == 0) sh.oflAny = 0;
    __syncthreads();

    int myc = 0;
    if (tid < BPB) {
        int vv = cnt2[(size_t)bc * BPB + tid];
        myc = vv & 0xFFFF;
        if (vv >> 16) atomicOr(&sh.oflAny, 1);
    }
    int x = myc;
    for (int off = 1; off < 64; off <<= 1) {
        int y = __shfl_up(x, off);
        if (lane >= off) x += y;
    }
    if (lane == 63 && wid < 2) sh.wtot[wid] = x;
    __syncthreads();
    const int excl = (wid == 0) ? (x - myc) : (sh.wtot[0] + x - myc);
    const int n = sh.wtot[0] + sh.wtot[1];
    const bool fb = (sh.oflAny != 0) || (n < KSEL) || (n > FASTN);

    if (!fb) {
        u64* list64 = (u64*)sh.sel.hist;
        if (tid < BPB) {
            for (int k = 0; k < myc; ++k) {            // coalesced: [k][part]
                uint2 p = cand2[((size_t)bc * PCAP + k) * BPB + tid];
                list64[excl + k] = ((u64)p.x << 32) | (u64)(~p.y);
            }
        }
        __syncthreads();
        u64 cl[RMAX];
        int pr[RMAX];
#pragma unroll
        for (int r = 0; r < RMAX; ++r) {
            int i = r * 64 + lane;
            cl[r] = (i < n) ? list64[i] : 0xFFFFFFFFFFFFFFFFull;
            pr[r] = 0;
        }
        const int js = (wid * n) >> 2;
        const int je = ((wid + 1) * n) >> 2;
        int j = js;
        for (; j + 3 < je; j += 4) {
            u64 o0 = list64[j];
            u64 o1 = list64[j + 1];
            u64 o2 = list64[j + 2];
            u64 o3 = list64[j + 3];
#pragma unroll
            for (int r = 0; r < RMAX; ++r)
                pr[r] += (o0 > cl[r]) + (o1 > cl[r]) + (o2 > cl[r]) + (o3 > cl[r]);
        }
        for (; j < je; ++j) {
            u64 o = list64[j];
#pragma unroll
            for (int r = 0; r < RMAX; ++r) pr[r] += (o > cl[r]);
        }
#pragma unroll
        for (int r = 0; r < RMAX; ++r) {
            int i = r * 64 + lane;
            if (i < n) sh.prank[wid][i] = (uint16_t)pr[r];
        }
        __syncthreads();
        for (int i = tid; i < n; i += 256) {
            int rank = (int)sh.prank[0][i] + (int)sh.prank[1][i]
                     + (int)sh.prank[2][i] + (int)sh.prank[3][i];
            if (rank < KSEL) {
                u64 e = list64[i];
                sh.sel.sKey[rank] = (uint32_t)(e >> 32);
                sh.sel.sIdx[rank] = (int)(~(uint32_t)e);
            }
        }
        __syncthreads();
    } else {
        const float* src = pred + (size_t)b * NANCH * PREDC + 4 + c;
        auto g = [src](int i) { KT e; e.key = f2key(sigm(src[(size_t)i * PREDC])); e.tie = i; return e; };
        block_select(g, NANCH, KSEL, sh.sel);
    }

    for (int xx = tid; xx < KSEL * 4; xx += 256) ((uint32_t*)sh.sup)[xx] = 0;
    if (tid < KSEL) {
        int ni = sh.sel.sIdx[tid];
        float4 pv = reinterpret_cast<const float4*>(pred)[((size_t)b * NANCH + ni) * (PREDC / 4)];
        float bx[4]; decode_box(pv, ni, dt, bx);
        sh.sbox[tid][0] = bx[0]; sh.sbox[tid][1] = bx[1];
        sh.sbox[tid][2] = bx[2]; sh.sbox[tid][3] = bx[3];
        sh.sarea[tid] = __fmul_rn(__fsub_rn(bx[2], bx[0]), __fsub_rn(bx[3], bx[1]));
        sh.sconf[tid] = (key2f(sh.sel.sKey[tid]) > 0.05f) ? 1 : 0;
    }
    __syncthreads();

    for (int pidx = tid; pidx < KSEL * KSEL; pidx += 256) {
        int i = pidx / KSEL;
        int jj = pidx - i * KSEL;
        if (jj > i && sh.sconf[i] && sh.sconf[jj]) {
            float x1 = fmaxf(sh.sbox[i][0], sh.sbox[jj][0]);
            float y1 = fmaxf(sh.sbox[i][1], sh.sbox[jj][1]);
            float x2 = fminf(sh.sbox[i][2], sh.sbox[jj][2]);
            float y2 = fminf(sh.sbox[i][3], sh.sbox[jj][3]);
            float iw = fmaxf(__fsub_rn(x2, x1), 0.0f);
            float ih = fmaxf(__fsub_rn(y2, y1), 0.0f);
            float inter = __fmul_rn(iw, ih);
            float uni = __fsub_rn(__fadd_rn(sh.sarea[i], sh.sarea[jj]), inter);
            if (__fdiv_rn(inter, fmaxf(uni, 1e-8f)) > 0.5f)
                atomicOr(&sh.sup[i][jj >> 5], 1u << (jj & 31));
        }
    }
    __syncthreads();

    if (tid < 64) {
        const int l = tid;
        uint4 rowA = *reinterpret_cast<const uint4*>(sh.sup[l]);
        int confA = sh.sconf[l];
        uint4 rowB = make_uint4(0u, 0u, 0u, 0u);
        int confB = 0;
        if (l + 64 < KSEL) {
            rowB = *reinterpret_cast<const uint4*>(sh.sup[l + 64]);
            confB = sh.sconf[l + 64];
        }
        u64 mA = __ballot(confA != 0);
        u64 mB = __ballot(confB != 0);
        uint32_t k0 = (uint32_t)mA, k1 = (uint32_t)(mA >> 32);
        uint32_t k2 = (uint32_t)mB, k3 = (uint32_t)(mB >> 32);
        for (int i = 0; i < KSEL; ++i) {
            uint32_t w = (i < 32) ? k0 : (i < 64) ? k1 : (i < 96) ? k2 : k3;
            if ((w >> (i & 31)) & 1u) {
                uint32_t s0, s1, s2, s3;
                if (i < 64) {
                    s0 = __shfl(rowA.x, i); s1 = __shfl(rowA.y, i);
                    s2 = __shfl(rowA.z, i); s3 = __shfl(rowA.w, i);
                } else {
                    s0 = __shfl(rowB.x, i - 64); s1 = __shfl(rowB.y, i - 64);
                    s2 = __shfl(rowB.z, i - 64); s3 = __shfl(rowB.w, i - 64);
                }
                k0 &= ~s0; k1 &= ~s1; k2 &= ~s2; k3 &= ~s3;
            }
        }
        if (l == 0) {
            sh.keepm[0] = k0; sh.keepm[1] = k1; sh.keepm[2] = k2; sh.keepm[3] = k3;
            posCntC[bc] = __popc(k0) + __popc(k1) + __popc(k2) + __popc(k3);
        }
    }
    __syncthreads();

    if (tid < KSEL) {
        reinterpret_cast<float4*>(cls_boxes)[(size_t)b * NFLAT + c * KSEL + tid] =
            make_float4(sh.sbox[tid][0], sh.sbox[tid][1], sh.sbox[tid][2], sh.sbox[tid][3]);
        int w = tid >> 5, bit = tid & 31;
        if ((sh.keepm[w] >> bit) & 1u) {
            int off = __popc(sh.keepm[w] & ((bit == 0) ? 0u : ((1u << bit) - 1u)));
            for (int ww = 0; ww < w; ++ww) off += __popc(sh.keepm[ww]);
            posKeyC[(size_t)bc * KSEL + off] = sh.sel.sKey[tid];
            posFlatC[(size_t)bc * KSEL + off] = (uint32_t)(c * KSEL + tid);
        }
    }
}

// ---------------- phase 3: per-(batch, 5-class group) top-100 ----------------
__device__ void phase_chunk(const uint32_t* __restrict__ posKeyC,
                            const uint32_t* __restrict__ posFlatC,
                            const int* __restrict__ posCntC,
                            u64* __restrict__ chunkOut, int* __restrict__ chunkN,
                            int blk, char* smemc) {
    ChunkSh& sh = *reinterpret_cast<ChunkSh*>(smemc);
    const int b = blk / NCHUNK;
    const int g = blk - b * NCHUNK;
    const int tid = threadIdx.x;
    const int lane = tid & 63;
    const int wid = tid >> 6;
    const int c0 = g * CGRP;

    if (tid == 0) {
        int acc = 0;
        for (int cc = 0; cc < CGRP; ++cc) {
            sh.csh[cc] = acc;
            acc += posCntC[b * NCLS + c0 + cc];
        }
        sh.csh[CGRP] = acc;
    }
    __syncthreads();
    const int n = sh.csh[CGRP];

    for (int idx = tid; idx < CGRP * KSEL; idx += 256) {
        int cc = idx / KSEL;
        int k = idx - cc * KSEL;
        int base = sh.csh[cc];
        if (k < sh.csh[cc + 1] - base) {
            size_t sp = (size_t)(b * NCLS + c0 + cc) * KSEL + k;
            sh.list64[base + k] = ((u64)posKeyC[sp] << 32) | (u64)(~posFlatC[sp]);
        }
    }
    __syncthreads();

    if (n > 0) {
        u64 cl[RMAX];
        int pr[RMAX];
#pragma unroll
        for (int r = 0; r < RMAX; ++r) {
            int i = r * 64 + lane;
            cl[r] = (i < n) ? sh.list64[i] : 0xFFFFFFFFFFFFFFFFull;
            pr[r] = 0;
        }
        const int js = (wid * n) >> 2;
        const int je = ((wid + 1) * n) >> 2;
        int j = js;
        for (; j + 3 < je; j += 4) {
            u64 o0 = sh.list64[j];
            u64 o1 = sh.list64[j + 1];
            u64 o2 = sh.list64[j + 2];
            u64 o3 = sh.list64[j + 3];
#pragma unroll
            for (int r = 0; r < RMAX; ++r)
                pr[r] += (o0 > cl[r]) + (o1 > cl[r]) + (o2 > cl[r]) + (o3 > cl[r]);
        }
        for (; j < je; ++j) {
            u64 o = sh.list64[j];
#pragma unroll
            for (int r = 0; r < RMAX; ++r) pr[r] += (o > cl[r]);
        }
#pragma unroll
        for (int r = 0; r < RMAX; ++r) {
            int i = r * 64 + lane;
            if (i < n) sh.prank[wid][i] = (uint16_t)pr[r];
        }
        __syncthreads();
        for (int i = tid; i < n; i += 256) {
            int rank = (int)sh.prank[0][i] + (int)sh.prank[1][i]
                     + (int)sh.prank[2][i] + (int)sh.prank[3][i];
            if (rank < KSEL) sh.osel[rank] = sh.list64[i];
        }
    }
    __syncthreads();
    const int kn = (n < KSEL) ? n : KSEL;
    if (tid < kn)
        chunkOut[(size_t)(b * NCHUNK + g) * KSEL + tid] = sh.osel[tid];
    if (tid == 0) chunkN[b * NCHUNK + g] = kn;
}

// ---------------- phase 4: 16-way tournament merge ---------------------------
__device__ void phase_merge(const u64* __restrict__ chunkOut,
                            const int* __restrict__ chunkN,
                            const float* __restrict__ cls_boxes,
                            float* __restrict__ out, int blk, char* smemc) {
    MergeSh& sh = *reinterpret_cast<MergeSh*>(smemc);
    const int b = blk;
    const int tid = threadIdx.x;

    if (tid < NCHUNK) sh.ln[tid] = chunkN[b * NCHUNK + tid];
    if (tid == 0) sh.okcnt = 0;
    __syncthreads();
    for (int x = tid; x < NCHUNK * KSEL; x += 256) {
        int g = x / KSEL;
        int k = x - g * KSEL;
        sh.lst[g][k] = (k < sh.ln[g]) ? chunkOut[(size_t)(b * NCHUNK + g) * KSEL + k] : 0ull;
    }
    __syncthreads();

    if (tid < 64) {
        const int l = tid;
        u64 h = (l < NCHUNK) ? sh.lst[l][0] : 0ull;
        int p = 0;
        for (int r = 0; r < KSEL; ++r) {
            u64 m = h;
#pragma unroll
            for (int off = 8; off >= 1; off >>= 1) {
                u64 o = __shfl_xor(m, off);
                if (o > m) m = o;
            }
            if (l < NCHUNK && h == m && m != 0ull) {
                ++p;
                h = (p < sh.ln[l]) ? sh.lst[l][p] : 0ull;
            }
            if (l == 0) sh.osel[r] = m;
        }
    }
    __syncthreads();

    if (tid < KSEL) {
        u64 e = sh.osel[tid];
        float4 ob = make_float4(0.f, 0.f, 0.f, 0.f);
        float sv = 0.f, cv = 0.f;
        if (e != 0ull) {
            uint32_t key = (uint32_t)(e >> 32);
            int flat = (int)(~(uint32_t)e);
            sv = key2f(key);
            ob = reinterpret_cast<const float4*>(cls_boxes)[(size_t)b * NFLAT + flat];
            cv = (float)(flat / KSEL);
            atomicAdd(&sh.okcnt, 1);
        }
        reinterpret_cast<float4*>(out)[(size_t)b * KSEL + tid] = ob;
        out[NB * KSEL * 4 + b * KSEL + tid] = sv;
        out[NB * KSEL * 5 + b * KSEL + tid] = cv;
    }
    __syncthreads();
    if (tid == 0) out[NB * KSEL * 6 + b] = (float)sh.okcnt;
}

// ---------------- fused cooperative kernel -----------------------------------
__global__ __launch_bounds__(256, 4) void fused_all(
    const float4* predv, const float* pred, uint2* cand2, int* cnt2,
    float* cls_boxes, uint32_t* posKeyC, uint32_t* posFlatC, int* posCntC,
    u64* chunkOut, int* chunkN, float* out, DimsTable dt) {
    __shared__ AllSh smem;
    cg::grid_group grid = cg::this_grid();
    const int blk = blockIdx.x;

    phase_scan(predv, cand2, cnt2, blk, (char*)&smem);
    __threadfence();
    grid.sync();
    if (blk < NB * NCLS)
        phase_nms(pred, cand2, cnt2, cls_boxes, posKeyC, posFlatC, posCntC, dt,
                  blk, (char*)&smem);
    __threadfence();
    grid.sync();
    if (blk < NB * NCHUNK)
        phase_chunk(posKeyC, posFlatC, posCntC, chunkOut, chunkN, blk, (char*)&smem);
    __threadfence();
    grid.sync();
    if (blk < NB)
        phase_merge(chunkOut, chunkN, cls_boxes, out, blk, (char*)&smem);
}

// ---------------- fallback wrappers (non-cooperative) ------------------------
__global__ __launch_bounds__(256) void scan_k(const float4* predv, uint2* cand2,
                                              int* cnt2) {
    __shared__ ScanSh smem;
    phase_scan(predv, cand2, cnt2, blockIdx.x, (char*)&smem);
}
__global__ __launch_bounds__(256) void nms_k(const float* pred, const uint2* cand2,
                                             const int* cnt2, float* cls_boxes,
                                             uint32_t* posKeyC, uint32_t* posFlatC,
                                             int* posCntC, DimsTable dt) {
    __shared__ NmsSh smem;
    phase_nms(pred, cand2, cnt2, cls_boxes, posKeyC, posFlatC, posCntC, dt,
              blockIdx.x, (char*)&smem);
}
__global__ __launch_bounds__(256) void chunk_k(const uint32_t* posKeyC,
                                               const uint32_t* posFlatC,
                                               const int* posCntC, u64* chunkOut,
                                               int* chunkN) {
    __shared__ ChunkSh smem;
    phase_chunk(posKeyC, posFlatC, posCntC, chunkOut, chunkN, blockIdx.x,
                (char*)&smem);
}
__global__ __launch_bounds__(256) void merge_k(const u64* chunkOut, const int* chunkN,
                                               const float* cls_boxes, float* out) {
    __shared__ MergeSh smem;
    phase_merge(chunkOut, chunkN, cls_boxes, out, blockIdx.x, (char*)&smem);
}

// ---------------- host launcher ----------------------------------------------
extern "C" void kernel_launch(void* const* d_in, const int* in_sizes, int n_in,
                              void* d_out, int out_size, void* d_ws, size_t ws_size,
                              hipStream_t stream) {
    const float* pred = (const float*)d_in[1];
    const float4* predv = reinterpret_cast<const float4*>(pred);
    float* out = (float*)d_out;

    DimsTable dt;
    const double areasd[5] = {1024.0, 4096.0, 16384.0, 65536.0, 262144.0};
    const double ratios[3] = {0.5, 1.0, 2.0};
    const double scales[3] = {1.0, pow(2.0, 1.0 / 3.0), pow(2.0, 2.0 / 3.0)};
    for (int l = 0; l < 5; ++l)
        for (int ri = 0; ri < 3; ++ri) {
            double ah = sqrt(areasd[l] / ratios[ri]);
            double aw = areasd[l] / ah;
            for (int si = 0; si < 3; ++si) {
                dt.d[l][ri * 3 + si][0] = (float)(aw * scales[si]);
                dt.d[l][ri * 3 + si][1] = (float)(ah * scales[si]);
            }
        }

    // workspace layout (~17.5 MB)
    char* wsb = (char*)d_ws;
    int* posCntC = (int*)wsb;                                             // [640]
    int* chunkNb = posCntC + NB * NCLS;                                   // [128]
    uint2* cand2 = (uint2*)(wsb + 16384);                                 // [640][PCAP][BPB]
    int* cnt2 = (int*)(cand2 + (size_t)NB * NCLS * PCAP * BPB);           // [640][BPB]
    float* cls_boxes = (float*)(cnt2 + (size_t)NB * NCLS * BPB);          // [8][8000][4]
    uint32_t* posKeyC = (uint32_t*)(cls_boxes + (size_t)NB * NFLAT * 4);  // [640][100]
    uint32_t* posFlatC = posKeyC + (size_t)NB * NFLAT;                    // [640][100]
    u64* chunkOut = (u64*)(posFlatC + (size_t)NB * NFLAT);                // [128][100]

    int maxb = 0;
    hipError_t qerr = hipOccupancyMaxActiveBlocksPerMultiprocessor(
        &maxb, reinterpret_cast<const void*>(&fused_all), 256, 0);
    bool coop_ok = (qerr == hipSuccess) && (maxb >= 4);

    if (coop_ok) {
        void* args[] = {(void*)&predv, (void*)&pred, (void*)&cand2, (void*)&cnt2,
                        (void*)&cls_boxes, (void*)&posKeyC, (void*)&posFlatC,
                        (void*)&posCntC, (void*)&chunkOut, (void*)&chunkNb,
                        (void*)&out, (void*)&dt};
        hipError_t lerr = hipLaunchCooperativeKernel(
            reinterpret_cast<void*>(&fused_all), dim3(GRID_TOTAL), dim3(256),
            args, 0, stream);
        if (lerr != hipSuccess) {
            (void)hipGetLastError();
            coop_ok = false;
        }
    }
    if (!coop_ok) {
        scan_k<<<GRID_TOTAL, 256, 0, stream>>>(predv, cand2, cnt2);
        nms_k<<<NB * NCLS, 256, 0, stream>>>(pred, cand2, cnt2, cls_boxes,
                                             posKeyC, posFlatC, posCntC, dt);
        chunk_k<<<NB * NCHUNK, 256, 0, stream>>>(posKeyC, posFlatC, posCntC,
                                                 chunkOut, chunkNb);
        merge_k<<<NB, 256, 0, stream>>>(chunkOut, chunkNb, cls_boxes, out);
    }
}

// Round 15
// 113.249 us; speedup vs baseline: 1.0837x; 1.0837x over previous
//
#include <hip/hip_runtime.h>
#include <math.h>
#include <stdint.h>

#define NANCH 49104
#define NCLS 80
#define KSEL 100
#define NFLAT (NCLS * KSEL)
#define PREDC 84
#define NB 8
#define ECAP 128
#define BATF4 (NANCH * (PREDC / 4))        // 1,031,184 float4s per batch
#define BPB 256                             // parts (blocks) per batch
#define PCAP 16                             // per-(class,part) static slice cap
#define FASTN 512                           // fast-select list cap
#define RMAX 8                              // FASTN/64 register candidates per lane
#define CGRP 5                              // classes per chunk group
#define NCHUNK (NCLS / CGRP)                // 16 groups per batch
// z-threshold: score > sigmoid(2.5)=0.924; per-class 100th score at z=2.873±0.032
// -> 2.5 is ~12 sigma below (exact full-rescan fallback if ever violated)
#define THRL 2.5f

struct DimsTable { float d[5][9][2]; };
struct KT { uint32_t key; int tie; };
typedef unsigned long long u64;

__device__ __forceinline__ uint32_t f2key(float f) {
    uint32_t u = __float_as_uint(f);
    return u ^ (uint32_t((int32_t)u >> 31) | 0x80000000u);
}
__device__ __forceinline__ float key2f(uint32_t k) {
    uint32_t u = (k & 0x80000000u) ? (k ^ 0x80000000u) : ~k;
    return __uint_as_float(u);
}
__device__ __forceinline__ float sigm(float x) { return 1.0f / (1.0f + expf(-x)); }

__device__ __forceinline__ void decode_box(const float4 pv, int n,
                                           const DimsTable& dt, float box[4]) {
    int lev, base, fw, stride;
    if (n < 36864)      { lev = 0; base = 0;     fw = 64; stride = 8;   }
    else if (n < 46080) { lev = 1; base = 36864; fw = 32; stride = 16;  }
    else if (n < 48384) { lev = 2; base = 46080; fw = 16; stride = 32;  }
    else if (n < 48960) { lev = 3; base = 48384; fw = 8;  stride = 64;  }
    else                { lev = 4; base = 48960; fw = 4;  stride = 128; }
    int i = n - base;
    int k = i % 9;
    int cell = i / 9;
    int xq = cell % fw, yq = cell / fw;
    float cx = ((float)xq + 0.5f) * (float)stride;
    float cy = ((float)yq + 0.5f) * (float)stride;
    float aw = dt.d[lev][k][0];
    float ah = dt.d[lev][k][1];
    float tx = __fmul_rn(pv.x, 0.1f);
    float ty = __fmul_rn(pv.y, 0.1f);
    float tw = __fmul_rn(pv.z, 0.2f);
    float th = __fmul_rn(pv.w, 0.2f);
    float px = __fadd_rn(__fmul_rn(tx, aw), cx);
    float py = __fadd_rn(__fmul_rn(ty, ah), cy);
    float pw = __fmul_rn(expf(tw), aw);
    float ph = __fmul_rn(expf(th), ah);
    float hw = __fmul_rn(pw, 0.5f);
    float hh = __fmul_rn(ph, 0.5f);
    box[0] = __fsub_rn(px, hw);
    box[1] = __fsub_rn(py, hh);
    box[2] = __fadd_rn(px, hw);
    box[3] = __fadd_rn(py, hh);
}

struct alignas(16) SelSh {
    int hist[2048];           // overlaid as u64 list64[FASTN] (4 KB of 8 KB)
    int suffix[256];
    uint32_t candKey[KSEL];
    int candIdx[KSEL];
    uint32_t eIdx[ECAP];
    uint32_t sKey[KSEL];
    int sIdx[KSEL];
    int cntG, cntE, krem, newkrem, digit, flast, rmin;
    uint32_t prefix, thrKey;
};

// Exact top-min(K,N) by (key desc, tie asc); fills sh.sKey/sIdx sorted. 256 thr.
// Used only for the never-taken full-rescan fallback.
template <typename G>
__device__ int block_select(G get, int N, int K, SelSh& sh) {
    const int tid = threadIdx.x;
    int Ksel = (N < K) ? N : K;
    if (Ksel <= 0) return 0;

    if (N <= K) {
        if (tid < N) { KT e = get(tid); sh.candKey[tid] = e.key; sh.candIdx[tid] = e.tie; }
        __syncthreads();
        if (tid < N) {
            uint32_t mk = sh.candKey[tid]; int mi = sh.candIdx[tid];
            int rank = 0;
            for (int j = 0; j < N; ++j) {
                uint32_t kj = sh.candKey[j]; int ij = sh.candIdx[j];
                rank += (kj > mk) || (kj == mk && ij < mi);
            }
            sh.sKey[rank] = mk; sh.sIdx[rank] = mi;
        }
        __syncthreads();
        return Ksel;
    }

    if (tid == 0) { sh.krem = K; sh.prefix = 0; }
    for (int pass = 0; pass < 3; ++pass) {
        const int bins   = (pass == 2) ? 1024 : 2048;
        const int dshift = (pass == 0) ? 21 : (pass == 1 ? 10 : 0);
        const int fshift = (pass == 1) ? 21 : 10;
        const int dmask  = bins - 1;
        for (int j = tid; j < bins; j += 256) sh.hist[j] = 0;
        __syncthreads();
        const uint32_t pref = sh.prefix;
        for (int i = tid; i < N; i += 256) {
            uint32_t key = get(i).key;
            if (pass == 0) {
                atomicAdd(&sh.hist[(key >> dshift) & dmask], 1);
            } else if ((key >> fshift) == pref) {
                atomicAdd(&sh.hist[(key >> dshift) & dmask], 1);
            }
        }
        __syncthreads();
        const int cpb = bins / 256;
        const int base = tid * cpb;
        int lsum = 0;
        for (int j = 0; j < cpb; ++j) lsum += sh.hist[base + j];
        sh.suffix[tid] = lsum;
        __syncthreads();
        for (int off = 1; off < 256; off <<= 1) {
            int v = (tid + off < 256) ? sh.suffix[tid + off] : 0;
            __syncthreads();
            sh.suffix[tid] += v;
            __syncthreads();
        }
        {
            int cum = sh.suffix[tid] - lsum;
            const int krem = sh.krem;
            for (int j = cpb - 1; j >= 0; --j) {
                int cnt = sh.hist[base + j];
                if (cnt > 0 && cum < krem && cum + cnt >= krem) {
                    sh.digit = base + j;
                    sh.newkrem = krem - cum;
                }
                cum += cnt;
            }
        }
        __syncthreads();
        if (tid == 0) {
            sh.krem = sh.newkrem;
            if (pass == 0)      sh.prefix = (uint32_t)sh.digit;
            else if (pass == 1) sh.prefix = (sh.prefix << 11) | (uint32_t)sh.digit;
            else                sh.thrKey = (sh.prefix << 10) | (uint32_t)sh.digit;
        }
        __syncthreads();
    }

    if (tid == 0) { sh.cntG = 0; sh.cntE = 0; }
    __syncthreads();
    const uint32_t thr = sh.thrKey;
    for (int i = tid; i < N; i += 256) {
        KT e = get(i);
        if (e.key > thr) {
            int g = atomicAdd(&sh.cntG, 1);
            sh.candKey[g] = e.key; sh.candIdx[g] = e.tie;
        } else if (e.key == thr) {
            int idx = atomicAdd(&sh.cntE, 1);
            if (idx < ECAP) sh.eIdx[idx] = (uint32_t)e.tie;
        }
    }
    __syncthreads();
    const int need = sh.krem;
    const int nG = K - need;
    if (sh.cntE <= ECAP) {
        const int ce = sh.cntE;
        if (tid < ce) {
            uint32_t my = sh.eIdx[tid];
            int rank = 0;
            for (int j = 0; j < ce; ++j) rank += (sh.eIdx[j] < my);
            if (rank < need) { sh.candKey[nG + rank] = thr; sh.candIdx[nG + rank] = (int)my; }
        }
    } else {
        if (tid == 0) sh.flast = -1;
        __syncthreads();
        for (int t = 0; t < need; ++t) {
            if (tid == 0) sh.rmin = 0x7FFFFFFF;
            __syncthreads();
            const int fl = sh.flast;
            int lmin = 0x7FFFFFFF;
            for (int i = tid; i < N; i += 256) {
                KT e = get(i);
                if (e.key == thr && e.tie > fl) lmin = min(lmin, e.tie);
            }
            atomicMin(&sh.rmin, lmin);
            __syncthreads();
            if (tid == 0) { sh.candKey[nG + t] = thr; sh.candIdx[nG + t] = sh.rmin; sh.flast = sh.rmin; }
            __syncthreads();
        }
    }
    __syncthreads();
    if (tid < K) {
        uint32_t mk = sh.candKey[tid]; int mi = sh.candIdx[tid];
        int rank = 0;
        for (int j = 0; j < K; ++j) {
            uint32_t kj = sh.candKey[j]; int ij = sh.candIdx[j];
            rank += (kj > mk) || (kj == mk && ij < mi);
        }
        sh.sKey[rank] = mk; sh.sIdx[rank] = mi;
    }
    __syncthreads();
    return Ksel;
}

// ---------- kernel 1: coalesced scan -> static slices (no init, no atomics) --
__device__ __forceinline__ void procf4(float4 p, int v, int b,
                                       int* lcnt, uint2 (*buck)[PCAP]) {
    uint32_t q = (uint32_t)v / 21u;
    uint32_t j = (uint32_t)v - q * 21u;
    if (j == 0u) return;
    bool c0 = p.x > THRL, c1 = p.y > THRL, c2 = p.z > THRL, c3 = p.w > THRL;
    if (!(c0 | c1 | c2 | c3)) return;
    uint32_t row = q - (uint32_t)b * (uint32_t)NANCH;
    int cbase = ((int)j - 1) * 4;
    float vv[4] = {p.x, p.y, p.z, p.w};
    bool pp[4] = {c0, c1, c2, c3};
#pragma unroll
    for (int k = 0; k < 4; ++k) {
        if (pp[k]) {
            int c = cbase + k;
            uint32_t key = f2key(sigm(vv[k]));
            int slot = atomicAdd(&lcnt[c], 1);
            if (slot < PCAP) buck[c][slot] = make_uint2(key, row);
            // overflow (~2e-9): count stays in lcnt, flagged at flush
        }
    }
}

__global__ __launch_bounds__(256) void cand_scan(const float4* __restrict__ predv,
                                                 uint2* __restrict__ cand2,
                                                 int* __restrict__ cnt2) {
    __shared__ uint2 buck[NCLS][PCAP];     // 10 KB
    __shared__ int lcnt[NCLS];

    const int tid = threadIdx.x;
    const int b = blockIdx.x / BPB;
    const int part = blockIdx.x - b * BPB;
    const int CH = (BATF4 + BPB - 1) / BPB;

    for (int j = tid; j < NCLS; j += 256) lcnt[j] = 0;
    __syncthreads();

    int s = b * BATF4 + part * CH;
    int e = b * BATF4 + BATF4;
    if (s + CH < e) e = s + CH;

    int v = s + tid;
    for (; v + 7 * 256 < e; v += 8 * 256) {   // 8 independent loads in flight
        float4 a0 = predv[v];
        float4 a1 = predv[v + 1 * 256];
        float4 a2 = predv[v + 2 * 256];
        float4 a3 = predv[v + 3 * 256];
        float4 a4 = predv[v + 4 * 256];
        float4 a5 = predv[v + 5 * 256];
        float4 a6 = predv[v + 6 * 256];
        float4 a7 = predv[v + 7 * 256];
        procf4(a0, v,           b, lcnt, buck);
        procf4(a1, v + 1 * 256, b, lcnt, buck);
        procf4(a2, v + 2 * 256, b, lcnt, buck);
        procf4(a3, v + 3 * 256, b, lcnt, buck);
        procf4(a4, v + 4 * 256, b, lcnt, buck);
        procf4(a5, v + 5 * 256, b, lcnt, buck);
        procf4(a6, v + 6 * 256, b, lcnt, buck);
        procf4(a7, v + 7 * 256, b, lcnt, buck);
    }
    for (; v < e; v += 256)
        procf4(predv[v], v, b, lcnt, buck);
    __syncthreads();

    // static-slice flush (layout [b][c][k][part] for coalesced gather)
    if (tid < NCLS) {
        int lc = lcnt[tid];
        int val = (lc > PCAP) ? (PCAP | 0x10000) : lc;   // overflow flag bit 16
        cnt2[((size_t)b * NCLS + tid) * BPB + part] = val;
    }
    for (int x = tid; x < NCLS * PCAP; x += 256) {
        int c = x >> 4;                    // PCAP = 16
        int k = x & (PCAP - 1);
        int lc = lcnt[c];
        if (lc > PCAP) lc = PCAP;
        if (k < lc)
            cand2[((size_t)(b * NCLS + c) * PCAP + k) * BPB + part] = buck[c][k];
    }
}

// ---------- kernel 2: gather + wave-split rank-select + reg-shfl NMS ---------
__global__ __launch_bounds__(256) void nms_sel(const float* __restrict__ pred,
                                               const uint2* __restrict__ cand2,
                                               const int* __restrict__ cnt2,
                                               float* __restrict__ cls_boxes,
                                               uint32_t* __restrict__ posKeyC,
                                               uint32_t* __restrict__ posFlatC,
                                               int* __restrict__ posCntC,
                                               DimsTable dt) {
    __shared__ SelSh sh;
    __shared__ uint16_t prank[4][FASTN];   // 4 KB partial ranks
    __shared__ int wtot[4];
    __shared__ int oflAny;
    __shared__ float sbox[KSEL][4];
    __shared__ float sarea[KSEL];
    __shared__ int sconf[KSEL];
    __shared__ alignas(16) uint32_t sup[KSEL][4];
    __shared__ uint32_t keepm[4];
    const int c = blockIdx.x;
    const int b = blockIdx.y;
    const int tid = threadIdx.x;
    const int bc = b * NCLS + c;
    const int lane = tid & 63;
    const int wid = tid >> 6;

    if (tid == 0) oflAny = 0;
    __syncthreads();

    // ---- gather per-part counts (+overflow flag) + wave-shfl prefix ----
    int vv = cnt2[(size_t)bc * BPB + tid];             // BPB == 256 == blockDim
    int myc = vv & 0xFFFF;
    if (vv >> 16) atomicOr(&oflAny, 1);
    {
        int x = myc;
        for (int off = 1; off < 64; off <<= 1) {
            int y = __shfl_up(x, off);
            if (lane >= off) x += y;
        }
        if (lane == 63) wtot[wid] = x;
        __syncthreads();
        int base = 0;
#pragma unroll
        for (int w = 0; w < 4; ++w) if (w < wid) base += wtot[w];
        sh.suffix[tid] = base + x - myc;               // exclusive prefix
    }
    const int excl = sh.suffix[tid];
    const int n = wtot[0] + wtot[1] + wtot[2] + wtot[3];
    const bool fb = (oflAny != 0) || (n < KSEL) || (n > FASTN);

    if (!fb) {
        u64* list64 = (u64*)sh.hist;                   // 4 KB used of 8 KB
        for (int k = 0; k < myc; ++k) {                // coalesced: [k][part]
            uint2 p = cand2[((size_t)bc * PCAP + k) * BPB + tid];
            list64[excl + k] = ((u64)p.x << 32) | (u64)(~p.y);
        }
        __syncthreads();
        u64 cl[RMAX];
        int pr[RMAX];
#pragma unroll
        for (int r = 0; r < RMAX; ++r) {
            int i = r * 64 + lane;
            cl[r] = (i < n) ? list64[i] : 0xFFFFFFFFFFFFFFFFull;
            pr[r] = 0;
        }
        const int js = (wid * n) >> 2;
        const int je = ((wid + 1) * n) >> 2;
        int j = js;
        for (; j + 3 < je; j += 4) {
            u64 o0 = list64[j];
            u64 o1 = list64[j + 1];
            u64 o2 = list64[j + 2];
            u64 o3 = list64[j + 3];
#pragma unroll
            for (int r = 0; r < RMAX; ++r)
                pr[r] += (o0 > cl[r]) + (o1 > cl[r]) + (o2 > cl[r]) + (o3 > cl[r]);
        }
        for (; j < je; ++j) {
            u64 o = list64[j];
#pragma unroll
            for (int r = 0; r < RMAX; ++r) pr[r] += (o > cl[r]);
        }
#pragma unroll
        for (int r = 0; r < RMAX; ++r) {
            int i = r * 64 + lane;
            if (i < n) prank[wid][i] = (uint16_t)pr[r];
        }
        __syncthreads();
        for (int i = tid; i < n; i += 256) {
            int rank = (int)prank[0][i] + (int)prank[1][i]
                     + (int)prank[2][i] + (int)prank[3][i];
            if (rank < KSEL) {
                u64 e = list64[i];
                sh.sKey[rank] = (uint32_t)(e >> 32);
                sh.sIdx[rank] = (int)(~(uint32_t)e);
            }
        }
        __syncthreads();
    } else {
        // exact fallback: full strided scan (never taken on this data)
        const float* src = pred + (size_t)b * NANCH * PREDC + 4 + c;
        auto g = [src](int i) { KT e; e.key = f2key(sigm(src[(size_t)i * PREDC])); e.tie = i; return e; };
        block_select(g, NANCH, KSEL, sh);
    }

    // ---- decode the 100 boxes + conf flags ----
    for (int x = tid; x < KSEL * 4; x += 256) ((uint32_t*)sup)[x] = 0;
    if (tid < KSEL) {
        int ni = sh.sIdx[tid];
        float4 pv = reinterpret_cast<const float4*>(pred)[((size_t)b * NANCH + ni) * (PREDC / 4)];
        float bx[4]; decode_box(pv, ni, dt, bx);
        sbox[tid][0] = bx[0]; sbox[tid][1] = bx[1];
        sbox[tid][2] = bx[2]; sbox[tid][3] = bx[3];
        sarea[tid] = __fmul_rn(__fsub_rn(bx[2], bx[0]), __fsub_rn(bx[3], bx[1]));
        sconf[tid] = (key2f(sh.sKey[tid]) > 0.05f) ? 1 : 0;
    }
    __syncthreads();

    // ---- parallel IoU suppression matrix (j > i bits only) ----
    for (int pidx = tid; pidx < KSEL * KSEL; pidx += 256) {
        int i = pidx / KSEL;
        int jj = pidx - i * KSEL;
        if (jj > i && sconf[i] && sconf[jj]) {
            float x1 = fmaxf(sbox[i][0], sbox[jj][0]);
            float y1 = fmaxf(sbox[i][1], sbox[jj][1]);
            float x2 = fminf(sbox[i][2], sbox[jj][2]);
            float y2 = fminf(sbox[i][3], sbox[jj][3]);
            float iw = fmaxf(__fsub_rn(x2, x1), 0.0f);
            float ih = fmaxf(__fsub_rn(y2, y1), 0.0f);
            float inter = __fmul_rn(iw, ih);
            float uni = __fsub_rn(__fadd_rn(sarea[i], sarea[jj]), inter);
            if (__fdiv_rn(inter, fmaxf(uni, 1e-8f)) > 0.5f)
                atomicOr(&sup[i][jj >> 5], 1u << (jj & 31));
        }
    }
    __syncthreads();

    // ---- greedy over bitmask: rows in registers, shfl broadcast (wave 0) ----
    if (tid < 64) {
        const int l = tid;
        uint4 rowA = *reinterpret_cast<const uint4*>(sup[l]);
        int confA = sconf[l];
        uint4 rowB = make_uint4(0u, 0u, 0u, 0u);
        int confB = 0;
        if (l + 64 < KSEL) {
            rowB = *reinterpret_cast<const uint4*>(sup[l + 64]);
            confB = sconf[l + 64];
        }
        u64 mA = __ballot(confA != 0);
        u64 mB = __ballot(confB != 0);
        uint32_t k0 = (uint32_t)mA, k1 = (uint32_t)(mA >> 32);
        uint32_t k2 = (uint32_t)mB, k3 = (uint32_t)(mB >> 32);
        for (int i = 0; i < KSEL; ++i) {
            uint32_t w = (i < 32) ? k0 : (i < 64) ? k1 : (i < 96) ? k2 : k3;
            if ((w >> (i & 31)) & 1u) {
                uint32_t s0, s1, s2, s3;
                if (i < 64) {
                    s0 = __shfl(rowA.x, i); s1 = __shfl(rowA.y, i);
                    s2 = __shfl(rowA.z, i); s3 = __shfl(rowA.w, i);
                } else {
                    s0 = __shfl(rowB.x, i - 64); s1 = __shfl(rowB.y, i - 64);
                    s2 = __shfl(rowB.z, i - 64); s3 = __shfl(rowB.w, i - 64);
                }
                k0 &= ~s0; k1 &= ~s1; k2 &= ~s2; k3 &= ~s3;
            }
        }
        if (l == 0) {
            keepm[0] = k0; keepm[1] = k1; keepm[2] = k2; keepm[3] = k3;
            posCntC[bc] = __popc(k0) + __popc(k1) + __popc(k2) + __popc(k3);
        }
    }
    __syncthreads();

    // ---- write boxes + survivors (sorted desc by construction) --------------
    if (tid < KSEL) {
        reinterpret_cast<float4*>(cls_boxes)[(size_t)b * NFLAT + c * KSEL + tid] =
            make_float4(sbox[tid][0], sbox[tid][1], sbox[tid][2], sbox[tid][3]);
        int w = tid >> 5, bit = tid & 31;
        if ((keepm[w] >> bit) & 1u) {
            int off = __popc(keepm[w] & ((bit == 0) ? 0u : ((1u << bit) - 1u)));
            for (int ww = 0; ww < w; ++ww) off += __popc(keepm[ww]);
            posKeyC[(size_t)bc * KSEL + off] = sh.sKey[tid];
            posFlatC[(size_t)bc * KSEL + off] = (uint32_t)(c * KSEL + tid);
        }
    }
}

// ---------- kernel 3: per-(batch, 5-class group) exact top-100 ---------------
__global__ __launch_bounds__(256) void chunk_sel(const uint32_t* __restrict__ posKeyC,
                                                 const uint32_t* __restrict__ posFlatC,
                                                 const int* __restrict__ posCntC,
                                                 u64* __restrict__ chunkOut,
                                                 int* __restrict__ chunkN) {
    __shared__ u64 list64[FASTN];          // 4 KB
    __shared__ uint16_t prank[4][FASTN];   // 4 KB
    __shared__ int csh[CGRP + 1];
    __shared__ u64 osel[KSEL];
    const int g = blockIdx.x;
    const int b = blockIdx.y;
    const int tid = threadIdx.x;
    const int lane = tid & 63;
    const int wid = tid >> 6;
    const int c0 = g * CGRP;

    if (tid == 0) {
        int acc = 0;
        for (int cc = 0; cc < CGRP; ++cc) {
            csh[cc] = acc;
            acc += posCntC[b * NCLS + c0 + cc];
        }
        csh[CGRP] = acc;
    }
    __syncthreads();
    const int n = csh[CGRP];               // <= 500 < FASTN always (5*100)

    for (int idx = tid; idx < CGRP * KSEL; idx += 256) {
        int cc = idx / KSEL;
        int k = idx - cc * KSEL;
        int base = csh[cc];
        if (k < csh[cc + 1] - base) {
            size_t sp = (size_t)(b * NCLS + c0 + cc) * KSEL + k;
            list64[base + k] = ((u64)posKeyC[sp] << 32) | (u64)(~posFlatC[sp]);
        }
    }
    __syncthreads();

    if (n > 0) {
        u64 cl[RMAX];
        int pr[RMAX];
#pragma unroll
        for (int r = 0; r < RMAX; ++r) {
            int i = r * 64 + lane;
            cl[r] = (i < n) ? list64[i] : 0xFFFFFFFFFFFFFFFFull;
            pr[r] = 0;
        }
        const int js = (wid * n) >> 2;
        const int je = ((wid + 1) * n) >> 2;
        int j = js;
        for (; j + 3 < je; j += 4) {
            u64 o0 = list64[j];
            u64 o1 = list64[j + 1];
            u64 o2 = list64[j + 2];
            u64 o3 = list64[j + 3];
#pragma unroll
            for (int r = 0; r < RMAX; ++r)
                pr[r] += (o0 > cl[r]) + (o1 > cl[r]) + (o2 > cl[r]) + (o3 > cl[r]);
        }
        for (; j < je; ++j) {
            u64 o = list64[j];
#pragma unroll
            for (int r = 0; r < RMAX; ++r) pr[r] += (o > cl[r]);
        }
#pragma unroll
        for (int r = 0; r < RMAX; ++r) {
            int i = r * 64 + lane;
            if (i < n) prank[wid][i] = (uint16_t)pr[r];
        }
        __syncthreads();
        for (int i = tid; i < n; i += 256) {
            int rank = (int)prank[0][i] + (int)prank[1][i]
                     + (int)prank[2][i] + (int)prank[3][i];
            if (rank < KSEL) osel[rank] = list64[i];
        }
    }
    __syncthreads();
    const int kn = (n < KSEL) ? n : KSEL;
    if (tid < kn)
        chunkOut[(size_t)(b * NCHUNK + g) * KSEL + tid] = osel[tid];
    if (tid == 0) chunkN[b * NCHUNK + g] = kn;
}

// ---------- kernel 4: tournament merge of 16 sorted lists --------------------
__global__ __launch_bounds__(256) void merge_sel(const u64* __restrict__ chunkOut,
                                                 const int* __restrict__ chunkN,
                                                 const float* __restrict__ cls_boxes,
                                                 float* __restrict__ out) {
    __shared__ u64 lst[NCHUNK][KSEL];      // 12.8 KB
    __shared__ int ln[NCHUNK];
    __shared__ u64 osel[KSEL];
    __shared__ int okcnt;
    const int b = blockIdx.x;
    const int tid = threadIdx.x;

    if (tid < NCHUNK) ln[tid] = chunkN[b * NCHUNK + tid];
    if (tid == 0) okcnt = 0;
    __syncthreads();
    for (int x = tid; x < NCHUNK * KSEL; x += 256) {
        int g = x / KSEL;
        int k = x - g * KSEL;
        lst[g][k] = (k < ln[g]) ? chunkOut[(size_t)(b * NCHUNK + g) * KSEL + k] : 0ull;
    }
    __syncthreads();

    if (tid < 64) {
        const int l = tid;
        u64 h = (l < NCHUNK) ? lst[l][0] : 0ull;   // 0 if empty
        int p = 0;
        for (int r = 0; r < KSEL; ++r) {
            u64 m = h;
#pragma unroll
            for (int off = 8; off >= 1; off >>= 1) {
                u64 o = __shfl_xor(m, off);
                if (o > m) m = o;
            }
            // lanes 0-15 now hold the max over the 16 heads (distinct values)
            if (l < NCHUNK && h == m && m != 0ull) {
                ++p;
                h = (p < ln[l]) ? lst[l][p] : 0ull;
            }
            if (l == 0) osel[r] = m;
        }
    }
    __syncthreads();

    if (tid < KSEL) {
        u64 e = osel[tid];
        float4 ob = make_float4(0.f, 0.f, 0.f, 0.f);
        float sv = 0.f, cv = 0.f;
        if (e != 0ull) {
            uint32_t key = (uint32_t)(e >> 32);
            int flat = (int)(~(uint32_t)e);
            sv = key2f(key);
            ob = reinterpret_cast<const float4*>(cls_boxes)[(size_t)b * NFLAT + flat];
            cv = (float)(flat / KSEL);
            atomicAdd(&okcnt, 1);
        }
        reinterpret_cast<float4*>(out)[(size_t)b * KSEL + tid] = ob;
        out[NB * KSEL * 4 + b * KSEL + tid] = sv;
        out[NB * KSEL * 5 + b * KSEL + tid] = cv;
    }
    __syncthreads();
    if (tid == 0) out[NB * KSEL * 6 + b] = (float)okcnt;
}

// ---------- host launcher ----------------------------------------------------
extern "C" void kernel_launch(void* const* d_in, const int* in_sizes, int n_in,
                              void* d_out, int out_size, void* d_ws, size_t ws_size,
                              hipStream_t stream) {
    const float* pred = (const float*)d_in[1];
    float* out = (float*)d_out;

    DimsTable dt;
    const double areasd[5] = {1024.0, 4096.0, 16384.0, 65536.0, 262144.0};
    const double ratios[3] = {0.5, 1.0, 2.0};
    const double scales[3] = {1.0, pow(2.0, 1.0 / 3.0), pow(2.0, 2.0 / 3.0)};
    for (int l = 0; l < 5; ++l)
        for (int ri = 0; ri < 3; ++ri) {
            double ah = sqrt(areasd[l] / ratios[ri]);
            double aw = areasd[l] / ah;
            for (int si = 0; si < 3; ++si) {
                dt.d[l][ri * 3 + si][0] = (float)(aw * scales[si]);
                dt.d[l][ri * 3 + si][1] = (float)(ah * scales[si]);
            }
        }

    // workspace layout (~23 MB)
    char* wsb = (char*)d_ws;
    int* posCntC = (int*)wsb;                                             // [640]
    int* chunkNb = posCntC + NB * NCLS;                                   // [128]
    uint2* cand2 = (uint2*)(wsb + 16384);                                 // [640][PCAP][BPB]
    int* cnt2 = (int*)(cand2 + (size_t)NB * NCLS * PCAP * BPB);           // [640][BPB]
    float* cls_boxes = (float*)(cnt2 + (size_t)NB * NCLS * BPB);          // [8][8000][4]
    uint32_t* posKeyC = (uint32_t*)(cls_boxes + (size_t)NB * NFLAT * 4);  // [640][100]
    uint32_t* posFlatC = posKeyC + (size_t)NB * NFLAT;                    // [640][100]
    u64* chunkOut = (u64*)(posFlatC + (size_t)NB * NFLAT);                // [128][100]

    cand_scan<<<NB * BPB, 256, 0, stream>>>(reinterpret_cast<const float4*>(pred),
                                            cand2, cnt2);

    dim3 gb(NCLS, NB);
    nms_sel<<<gb, 256, 0, stream>>>(pred, cand2, cnt2, cls_boxes,
                                    posKeyC, posFlatC, posCntC, dt);

    dim3 gc(NCHUNK, NB);
    chunk_sel<<<gc, 256, 0, stream>>>(posKeyC, posFlatC, posCntC, chunkOut, chunkNb);

    merge_sel<<<NB, 256, 0, stream>>>(chunkOut, chunkNb, cls_boxes, out);
}